// Round 1
// baseline (293.083 us; speedup 1.0000x reference)
//
#include <hip/hip_runtime.h>
#include <hip/hip_bf16.h>

#define E_ 32
#define H_ 1024
#define I_ 768
#define I2_ 1536
#define T_ 4096
#define K_ 4
#define CAP_ 1024
#define NSLOT_ (E_*CAP_)

typedef __attribute__((ext_vector_type(8))) short short8;
typedef __attribute__((ext_vector_type(4))) float f32x4;

__device__ __forceinline__ short f2bf(float f) {
    __hip_bfloat16 h = __float2bfloat16(f);
    return __builtin_bit_cast(short, h);
}

typedef __attribute__((address_space(3))) void lds_void;
typedef const __attribute__((address_space(1))) void glob_void;

__device__ __forceinline__ void gload16(const void* g, void* l) {
    __builtin_amdgcn_global_load_lds((glob_void*)g, (lds_void*)l, 16, 0, 0);
}

// ---------------- routing ----------------

__global__ void k_init(int* __restrict__ cursor, int* __restrict__ s_tok,
                       float* __restrict__ s_w) {
    int i = blockIdx.x * 256 + threadIdx.x;
    if (i < E_) cursor[i] = 0;
    if (i < NSLOT_) { s_tok[i] = 0; s_w[i] = 0.f; }
}

__global__ void k_cast(const float* __restrict__ hs, short* __restrict__ Xb) {
    int i = blockIdx.x * 256 + threadIdx.x;   // 8 elements per thread
    const float* p = hs + (size_t)i * 8;
    f32x4 a = *(const f32x4*)p;
    f32x4 b = *(const f32x4*)(p + 4);
    short8 o;
    o[0]=f2bf(a[0]); o[1]=f2bf(a[1]); o[2]=f2bf(a[2]); o[3]=f2bf(a[3]);
    o[4]=f2bf(b[0]); o[5]=f2bf(b[1]); o[6]=f2bf(b[2]); o[7]=f2bf(b[3]);
    *(short8*)(Xb + (size_t)i * 8) = o;
}

__global__ void k_scatter(const int* __restrict__ tki, const float* __restrict__ tkw,
                          int* __restrict__ cursor, int* __restrict__ s_tok,
                          float* __restrict__ s_w) {
    int n = blockIdx.x * 256 + threadIdx.x;
    if (n >= T_ * K_) return;
    int e = tki[n];
    int p = atomicAdd(cursor + e, 1);
    if (p < CAP_) {
        s_tok[e * CAP_ + p] = n >> 2;   // K_ == 4
        s_w[e * CAP_ + p]   = tkw[n];
    }
}

// ---------------- GEMM1 + SwiGLU ----------------
// Per block: 128 token-rows x (64 gate cols + paired 64 up cols) for one expert.
// 4 waves as 2(M) x 2(N); per wave 64 rows x 32 gate + 32 up cols.
__global__ __launch_bounds__(256) void k_gemm1(
    const short* __restrict__ Xb, const float* __restrict__ W1,
    const int* __restrict__ s_tok, const int* __restrict__ counts,
    short* __restrict__ Hb)
{
    __shared__ alignas(16) short As[128 * 32];   // bf16 tile [128][32], swizzled chunks
    __shared__ alignas(16) float Bg[64 * 32];    // fp32 gate tile [64][32]
    __shared__ alignas(16) float Bu[64 * 32];    // fp32 up tile

    const int NT = I_ / 64;                      // 12
    int bid = blockIdx.x;
    int e   = bid / (8 * NT);
    int rem = bid % (8 * NT);
    int mt = rem / NT, nt = rem % NT;
    int cnt = min(counts[e], CAP_);
    int row0 = mt * 128;
    if (row0 >= cnt) return;
    int gc0 = nt * 64;

    int tid = threadIdx.x, wid = tid >> 6, lane = tid & 63;
    int wm = wid >> 1, wn = wid & 1;

    // A staging: 8 instrs of 64x16B; wave handles i = wid*2+{0,1}. chunk=(i*64+lane)
    int cA0 = (wid * 2 + 0) * 64 + lane, cA1 = (wid * 2 + 1) * 64 + lane;
    int rA0 = cA0 >> 2, rA1 = cA1 >> 2;          // 4 chunks (16B of bf16) per row
    int tok0 = s_tok[e * CAP_ + row0 + rA0];
    int tok1 = s_tok[e * CAP_ + row0 + rA1];
    const short* srcA0 = Xb + (size_t)tok0 * H_ + (((cA0 & 3) ^ (rA0 & 3)) * 8);
    const short* srcA1 = Xb + (size_t)tok1 * H_ + (((cA1 & 3) ^ (rA1 & 3)) * 8);
    short* dstA0 = As + (wid * 2 + 0) * 512;
    short* dstA1 = As + (wid * 2 + 1) * 512;

    // B staging: 8 instrs each for gate/up; 8 chunks per fp32 row
    const float* w1e = W1 + (size_t)e * I2_ * H_;
    int rB0 = cA0 >> 3, rB1 = cA1 >> 3;
    int sB0 = ((cA0 & 7) ^ (rB0 & 7)) * 4, sB1 = ((cA1 & 7) ^ (rB1 & 7)) * 4;
    const float* srcG0 = w1e + (size_t)(gc0 + rB0) * H_ + sB0;
    const float* srcG1 = w1e + (size_t)(gc0 + rB1) * H_ + sB1;
    const float* srcU0 = w1e + (size_t)(768 + gc0 + rB0) * H_ + sB0;
    const float* srcU1 = w1e + (size_t)(768 + gc0 + rB1) * H_ + sB1;
    float* dstG0 = Bg + (wid * 2 + 0) * 256;
    float* dstG1 = Bg + (wid * 2 + 1) * 256;
    float* dstU0 = Bu + (wid * 2 + 0) * 256;
    float* dstU1 = Bu + (wid * 2 + 1) * 256;

    f32x4 accg[4][2], accu[4][2];
#pragma unroll
    for (int m = 0; m < 4; ++m)
#pragma unroll
        for (int n = 0; n < 2; ++n) {
            accg[m][n] = (f32x4){0.f, 0.f, 0.f, 0.f};
            accu[m][n] = (f32x4){0.f, 0.f, 0.f, 0.f};
        }

    for (int kt = 0; kt < H_ / 32; ++kt) {
        int k0 = kt * 32;
        gload16(srcA0 + k0, dstA0);
        gload16(srcA1 + k0, dstA1);
        gload16(srcG0 + k0, dstG0);
        gload16(srcG1 + k0, dstG1);
        gload16(srcU0 + k0, dstU0);
        gload16(srcU1 + k0, dstU1);
        __syncthreads();   // compiler drains vmcnt before s_barrier

        short8 a[4];
#pragma unroll
        for (int m = 0; m < 4; ++m) {
            int row = wm * 64 + m * 16 + (lane & 15);
            int c = (lane >> 4) ^ (row & 3);
            a[m] = *(const short8*)&As[row * 32 + c * 8];
        }
        short8 bg[2], bu[2];
#pragma unroll
        for (int n = 0; n < 2; ++n) {
            int br = wn * 32 + n * 16 + (lane & 15);
            int c0 = (lane >> 4) * 2;
            f32x4 x = *(const f32x4*)&Bg[(br * 8 + (c0 ^ (br & 7))) * 4];
            f32x4 y = *(const f32x4*)&Bg[(br * 8 + ((c0 + 1) ^ (br & 7))) * 4];
            short8 t;
            t[0]=f2bf(x[0]); t[1]=f2bf(x[1]); t[2]=f2bf(x[2]); t[3]=f2bf(x[3]);
            t[4]=f2bf(y[0]); t[5]=f2bf(y[1]); t[6]=f2bf(y[2]); t[7]=f2bf(y[3]);
            bg[n] = t;
            x = *(const f32x4*)&Bu[(br * 8 + (c0 ^ (br & 7))) * 4];
            y = *(const f32x4*)&Bu[(br * 8 + ((c0 + 1) ^ (br & 7))) * 4];
            t[0]=f2bf(x[0]); t[1]=f2bf(x[1]); t[2]=f2bf(x[2]); t[3]=f2bf(x[3]);
            t[4]=f2bf(y[0]); t[5]=f2bf(y[1]); t[6]=f2bf(y[2]); t[7]=f2bf(y[3]);
            bu[n] = t;
        }
#pragma unroll
        for (int m = 0; m < 4; ++m)
#pragma unroll
            for (int n = 0; n < 2; ++n) {
                accg[m][n] = __builtin_amdgcn_mfma_f32_16x16x32_bf16(a[m], bg[n], accg[m][n], 0, 0, 0);
                accu[m][n] = __builtin_amdgcn_mfma_f32_16x16x32_bf16(a[m], bu[n], accu[m][n], 0, 0, 0);
            }
        __syncthreads();
    }

    // SwiGLU epilogue: gate/up are elementwise-paired in registers.
#pragma unroll
    for (int m = 0; m < 4; ++m) {
        int rbase = wm * 64 + m * 16 + ((lane >> 4) * 4);
#pragma unroll
        for (int n = 0; n < 2; ++n) {
            int col = gc0 + wn * 32 + n * 16 + (lane & 15);
#pragma unroll
            for (int q = 0; q < 4; ++q) {
                float g = accg[m][n][q], u = accu[m][n][q];
                float h = (g / (1.f + __expf(-g))) * u;
                Hb[(size_t)(e * CAP_ + row0 + rbase + q) * I_ + col] = f2bf(h);
            }
        }
    }
}

// ---------------- GEMM2 + weighted scatter ----------------
__global__ __launch_bounds__(256) void k_gemm2(
    const short* __restrict__ Hb, const float* __restrict__ W2,
    const int* __restrict__ s_tok, const float* __restrict__ s_w,
    const int* __restrict__ counts, float* __restrict__ out)
{
    __shared__ alignas(16) short Ah[128 * 32];   // bf16 [128][32]
    __shared__ alignas(16) float Bs[128 * 32];   // fp32 [128][32]

    int bid = blockIdx.x;
    int e = bid / 64;            // 8 m-tiles x 8 n-tiles
    int rem = bid % 64;
    int mt = rem / 8, nt = rem % 8;
    int cnt = min(counts[e], CAP_);
    int row0 = mt * 128;
    if (row0 >= cnt) return;
    int nc0 = nt * 128;

    int tid = threadIdx.x, wid = tid >> 6, lane = tid & 63;
    int wm = wid >> 1, wn = wid & 1;

    int cA0 = (wid * 2 + 0) * 64 + lane, cA1 = (wid * 2 + 1) * 64 + lane;
    int rA0 = cA0 >> 2, rA1 = cA1 >> 2;
    const short* srcA0 = Hb + (size_t)(e * CAP_ + row0 + rA0) * I_ + (((cA0 & 3) ^ (rA0 & 3)) * 8);
    const short* srcA1 = Hb + (size_t)(e * CAP_ + row0 + rA1) * I_ + (((cA1 & 3) ^ (rA1 & 3)) * 8);
    short* dstA0 = Ah + (wid * 2 + 0) * 512;
    short* dstA1 = Ah + (wid * 2 + 1) * 512;

    const float* w2e = W2 + (size_t)e * H_ * I_;
    const float* srcB[4];
    float* dstB[4];
#pragma unroll
    for (int j = 0; j < 4; ++j) {
        int c = (wid * 4 + j) * 64 + lane;
        int r = c >> 3;
        srcB[j] = w2e + (size_t)(nc0 + r) * I_ + (((c & 7) ^ (r & 7)) * 4);
        dstB[j] = Bs + (wid * 4 + j) * 256;
    }

    f32x4 acc[4][4];
#pragma unroll
    for (int m = 0; m < 4; ++m)
#pragma unroll
        for (int n = 0; n < 4; ++n) acc[m][n] = (f32x4){0.f, 0.f, 0.f, 0.f};

    for (int kt = 0; kt < I_ / 32; ++kt) {
        int k0 = kt * 32;
        gload16(srcA0 + k0, dstA0);
        gload16(srcA1 + k0, dstA1);
#pragma unroll
        for (int j = 0; j < 4; ++j) gload16(srcB[j] + k0, dstB[j]);
        __syncthreads();

        short8 a[4];
#pragma unroll
        for (int m = 0; m < 4; ++m) {
            int row = wm * 64 + m * 16 + (lane & 15);
            int c = (lane >> 4) ^ (row & 3);
            a[m] = *(const short8*)&Ah[row * 32 + c * 8];
        }
        short8 b[4];
#pragma unroll
        for (int n = 0; n < 4; ++n) {
            int br = wn * 64 + n * 16 + (lane & 15);
            int c0 = (lane >> 4) * 2;
            f32x4 x = *(const f32x4*)&Bs[(br * 8 + (c0 ^ (br & 7))) * 4];
            f32x4 y = *(const f32x4*)&Bs[(br * 8 + ((c0 + 1) ^ (br & 7))) * 4];
            short8 t;
            t[0]=f2bf(x[0]); t[1]=f2bf(x[1]); t[2]=f2bf(x[2]); t[3]=f2bf(x[3]);
            t[4]=f2bf(y[0]); t[5]=f2bf(y[1]); t[6]=f2bf(y[2]); t[7]=f2bf(y[3]);
            b[n] = t;
        }
#pragma unroll
        for (int m = 0; m < 4; ++m)
#pragma unroll
            for (int n = 0; n < 4; ++n)
                acc[m][n] = __builtin_amdgcn_mfma_f32_16x16x32_bf16(a[m], b[n], acc[m][n], 0, 0, 0);
        __syncthreads();
    }

#pragma unroll
    for (int m = 0; m < 4; ++m) {
#pragma unroll
        for (int q = 0; q < 4; ++q) {
            int i = row0 + wm * 64 + m * 16 + ((lane >> 4) * 4) + q;
            if (i < cnt) {
                int tok = s_tok[e * CAP_ + i];
                float w = s_w[e * CAP_ + i];
#pragma unroll
                for (int n = 0; n < 4; ++n) {
                    atomicAdd(out + (size_t)tok * H_ + nc0 + wn * 64 + n * 16 + (lane & 15),
                              acc[m][n][q] * w);
                }
            }
        }
    }
}

// ---------------- launch ----------------

extern "C" void kernel_launch(void* const* d_in, const int* in_sizes, int n_in,
                              void* d_out, int out_size, void* d_ws, size_t ws_size,
                              hipStream_t stream) {
    const float* hs  = (const float*)d_in[0];
    const int*   tki = (const int*)d_in[1];
    const float* tkw = (const float*)d_in[2];
    const float* w1  = (const float*)d_in[3];
    const float* w2  = (const float*)d_in[4];
    float* out = (float*)d_out;

    char* ws = (char*)d_ws;
    int*   cursor = (int*)ws;                                  // 128 B
    int*   s_tok  = (int*)(ws + 4096);                         // 128 KB
    float* s_w    = (float*)(ws + 4096 + NSLOT_ * 4);          // 128 KB
    short* Xb     = (short*)(ws + 4096 + NSLOT_ * 8);          // 8 MB
    short* Hb     = (short*)(ws + 4096 + NSLOT_ * 8 + (size_t)T_ * H_ * 2);  // 48 MB
    // total ws use ~= 56.3 MB

    hipMemsetAsync(d_out, 0, (size_t)T_ * H_ * 4, stream);
    hipLaunchKernelGGL(k_init, dim3(NSLOT_ / 256), dim3(256), 0, stream, cursor, s_tok, s_w);
    hipLaunchKernelGGL(k_cast, dim3((T_ * H_ / 8) / 256), dim3(256), 0, stream, hs, Xb);
    hipLaunchKernelGGL(k_scatter, dim3((T_ * K_) / 256), dim3(256), 0, stream, tki, tkw, cursor, s_tok, s_w);
    hipLaunchKernelGGL(k_gemm1, dim3(E_ * 8 * (I_ / 64)), dim3(256), 0, stream, Xb, w1, s_tok, cursor, Hb);
    hipLaunchKernelGGL(k_gemm2, dim3(E_ * 8 * 8), dim3(256), 0, stream, Hb, w2, s_tok, s_w, cursor, out);
}